// Round 2
// baseline (2627.515 us; speedup 1.0000x reference)
//
#include <hip/hip_runtime.h>

typedef unsigned short u16;
typedef unsigned int   u32;

using f32x4  = __attribute__((ext_vector_type(4))) float;
using bf16x8 = __attribute__((ext_vector_type(8))) __bf16;

// ---------- helpers ----------
__device__ inline u16 f2bf(float f) {
  u32 u = __builtin_bit_cast(u32, f);
  u32 r = (u + 0x7FFFu + ((u >> 16) & 1u)) >> 16;   // RNE
  return (u16)r;
}
__device__ inline float bf2f(u16 v) {
  u32 u = ((u32)v) << 16;
  return __builtin_bit_cast(float, u);
}

// Geometry: B=8, H=W=128, NW=8, win=16x16 (N=256), D=256, shift=8.
// All indices below are CHUNK-LOCAL (batch-separable problem).
// linear token m -> windowed row (after roll(-8,-8) + partition)
__device__ inline int perm_fwd(int m) {
  int b = m >> 14, rem = m & 16383;
  int h = rem >> 7, w = rem & 127;
  int hr = (h - 8) & 127, wr = (w - 8) & 127;
  int win = (b << 6) | ((hr >> 4) << 3) | (wr >> 4);
  return (win << 8) | ((hr & 15) << 4) | (wr & 15);
}
// windowed row -> linear token (merge + roll(+8,+8))
__device__ inline int perm_inv(int r) {
  int win = r >> 8, t = r & 255;
  int b = win >> 6, wy = (win >> 3) & 7, wx = win & 7;
  int h = (((wy << 4) | (t >> 4)) + 8) & 127;
  int w = (((wx << 4) | (t & 15)) + 8) & 127;
  return (b << 14) | (h << 7) | w;
}

// ---------- generic 128x128x(BK=32) NT GEMM, bf16 in / fp32 acc ----------
#define LDSS 40   // 32 + 8 pad (bf16 elems); row stride 80 B

enum { MODE_QKV = 0, MODE_SCORES = 1, MODE_PV = 2, MODE_F32 = 3, MODE_FFN1 = 4 };

template<int MODE>
__global__ __launch_bounds__(256)
void gemm_nt(const u16* __restrict__ A, int lda, long long sAz,
             const u16* __restrict__ Bt, int ldb, long long sBz,
             u16* __restrict__ OutB, float* __restrict__ OutF,
             const float* __restrict__ mask, int K, int accumulate)
{
  __shared__ __align__(16) u16 sA[128 * LDSS];
  __shared__ __align__(16) u16 sB[128 * LDSS];

  const int tid  = threadIdx.x;
  const int lane = tid & 63;
  const int wave = tid >> 6;
  const int l15  = lane & 15;
  const int quad = lane >> 4;
  const int wm   = (wave >> 1) << 6;
  const int wn   = (wave & 1) << 6;
  const int z    = blockIdx.z;
  const int m0   = blockIdx.x << 7;
  const int n0   = blockIdx.y << 7;

  const u16* Ab = A  + (long long)z * sAz;
  const u16* Bb = Bt + (long long)z * sBz;

  const f32x4 zero = {0.f, 0.f, 0.f, 0.f};
  f32x4 acc[4][4];
#pragma unroll
  for (int i = 0; i < 4; ++i)
#pragma unroll
    for (int j = 0; j < 4; ++j) acc[i][j] = zero;

  for (int k0 = 0; k0 < K; k0 += 32) {
    __syncthreads();
#pragma unroll
    for (int p = 0; p < 2; ++p) {
      int idx = tid + (p << 8);
      int row = idx >> 2;
      int ce  = (idx & 3) << 3;
      uint4 va = *(const uint4*)(Ab + (long long)(m0 + row) * lda + k0 + ce);
      *(uint4*)(sA + row * LDSS + ce) = va;
      uint4 vb = *(const uint4*)(Bb + (long long)(n0 + row) * ldb + k0 + ce);
      *(uint4*)(sB + row * LDSS + ce) = vb;
    }
    __syncthreads();
    bf16x8 af[4], bfr[4];
#pragma unroll
    for (int i = 0; i < 4; ++i) {
      af[i]  = *(const bf16x8*)(sA + (wm + (i << 4) + l15) * LDSS + (quad << 3));
      bfr[i] = *(const bf16x8*)(sB + (wn + (i << 4) + l15) * LDSS + (quad << 3));
    }
#pragma unroll
    for (int i = 0; i < 4; ++i)
#pragma unroll
      for (int j = 0; j < 4; ++j)
        acc[i][j] = __builtin_amdgcn_mfma_f32_16x16x32_bf16(af[i], bfr[j], acc[i][j], 0, 0, 0);
  }

  // epilogue: D[row=quad*4+r][col=l15]
#pragma unroll
  for (int i = 0; i < 4; ++i) {
#pragma unroll
    for (int r = 0; r < 4; ++r) {
      int mg = m0 + wm + (i << 4) + (quad << 2) + r;
      if constexpr (MODE == MODE_QKV) {
        u16* orow = OutB + ((long long)perm_fwd(mg) << 8);
#pragma unroll
        for (int j = 0; j < 4; ++j) {
          int ng = n0 + wn + (j << 4) + l15;
          orow[ng] = f2bf(acc[i][j][r]);
        }
      } else if constexpr (MODE == MODE_SCORES) {
        const float* mrow = mask + (((long long)(z & 63)) << 16) + ((long long)mg << 8);
        u16* orow = OutB + (((long long)z) << 16) + ((long long)mg << 8);
#pragma unroll
        for (int j = 0; j < 4; ++j) {
          int ng = n0 + wn + (j << 4) + l15;
          orow[ng] = f2bf(acc[i][j][r] * 0.0625f + mrow[ng]);
        }
      } else if constexpr (MODE == MODE_PV) {
        u16* orow = OutB + ((long long)perm_inv((z << 8) + mg) << 8);
#pragma unroll
        for (int j = 0; j < 4; ++j) {
          int ng = n0 + wn + (j << 4) + l15;
          orow[ng] = f2bf(acc[i][j][r]);
        }
      } else if constexpr (MODE == MODE_F32) {
        float* orow = OutF + ((long long)mg << 8);
        if (accumulate) {
#pragma unroll
          for (int j = 0; j < 4; ++j) {
            int ng = n0 + wn + (j << 4) + l15;
            orow[ng] += acc[i][j][r];
          }
        } else {
#pragma unroll
          for (int j = 0; j < 4; ++j) {
            int ng = n0 + wn + (j << 4) + l15;
            orow[ng] = acc[i][j][r];
          }
        }
      } else { // MODE_FFN1: exact gelu -> bf16
        u16* orow = OutB + ((long long)mg << 8);
#pragma unroll
        for (int j = 0; j < 4; ++j) {
          int ng = n0 + wn + (j << 4) + l15;
          float v = acc[i][j][r];
          orow[ng] = f2bf(0.5f * v * (1.0f + erff(v * 0.70710678118654752f)));
        }
      }
    }
  }
}

// ---------- per-window 256x256 transpose (bf16) ----------
__global__ __launch_bounds__(256)
void transpose256(const u16* __restrict__ src, u16* __restrict__ dst)
{
  __shared__ u16 t[32][33];
  const int z  = blockIdx.z;
  const int tx = blockIdx.x << 5;
  const int ty = blockIdx.y << 5;
  const int c  = threadIdx.x & 31;
  const int r0 = threadIdx.x >> 5;
  const long long base = ((long long)z) << 16;
#pragma unroll
  for (int p = 0; p < 4; ++p) {
    int r = r0 + (p << 3);
    t[r][c] = src[base + (long long)(ty + r) * 256 + tx + c];
  }
  __syncthreads();
#pragma unroll
  for (int p = 0; p < 4; ++p) {
    int r = r0 + (p << 3);
    dst[base + (long long)(tx + r) * 256 + ty + c] = t[c][r];
  }
}

// ---------- in-place row softmax over 256 bf16 (1 wave/row) ----------
__global__ __launch_bounds__(256)
void softmax_rows(u16* __restrict__ SP)
{
  const int row  = (blockIdx.x << 2) + (threadIdx.x >> 6);
  const int lane = threadIdx.x & 63;
  u16* rp = SP + ((long long)row << 8);
  ushort4 u = *((const ushort4*)rp + lane);
  float x0 = bf2f(u.x), x1 = bf2f(u.y), x2 = bf2f(u.z), x3 = bf2f(u.w);
  float mx = fmaxf(fmaxf(x0, x1), fmaxf(x2, x3));
#pragma unroll
  for (int o = 32; o > 0; o >>= 1) mx = fmaxf(mx, __shfl_xor(mx, o));
  float e0 = __expf(x0 - mx), e1 = __expf(x1 - mx), e2 = __expf(x2 - mx), e3 = __expf(x3 - mx);
  float s = e0 + e1 + e2 + e3;
#pragma unroll
  for (int o = 32; o > 0; o >>= 1) s += __shfl_xor(s, o);
  float inv = 1.0f / s;
  ushort4 o4;
  o4.x = f2bf(e0 * inv); o4.y = f2bf(e1 * inv); o4.z = f2bf(e2 * inv); o4.w = f2bf(e3 * inv);
  *((ushort4*)rp + lane) = o4;
}

// ---------- LayerNorm variants (1 wave/row, 256 cols) ----------
// MODE 0: xcat[:, :256]   = bf16(ResF + LN(Y))
// MODE 1: xcat[:, 256:512]= bf16(LN(Y))
// MODE 2: OutF            = bf16res(xcat[:, :256]) + LN(Y)
template<int MODE>
__global__ __launch_bounds__(256)
void ln_kernel(const float* __restrict__ Y, const float* __restrict__ G,
               const float* __restrict__ Bb, const float* __restrict__ ResF,
               const u16* __restrict__ ResB,
               float* __restrict__ OutF, u16* __restrict__ OutB)
{
  const int row  = (blockIdx.x << 2) + (threadIdx.x >> 6);
  const int lane = threadIdx.x & 63;
  float4 x = *((const float4*)(Y + ((long long)row << 8)) + lane);
  float s  = x.x + x.y + x.z + x.w;
  float s2 = x.x * x.x + x.y * x.y + x.z * x.z + x.w * x.w;
#pragma unroll
  for (int o = 32; o > 0; o >>= 1) { s += __shfl_xor(s, o); s2 += __shfl_xor(s2, o); }
  float mean = s * (1.0f / 256.0f);
  float var  = s2 * (1.0f / 256.0f) - mean * mean;
  float rstd = rsqrtf(var + 1e-5f);
  float4 g = *((const float4*)G + lane);
  float4 b = *((const float4*)Bb + lane);
  float v0 = (x.x - mean) * rstd * g.x + b.x;
  float v1 = (x.y - mean) * rstd * g.y + b.y;
  float v2 = (x.z - mean) * rstd * g.z + b.z;
  float v3 = (x.w - mean) * rstd * g.w + b.w;
  if constexpr (MODE == 0) {
    float4 rr = *((const float4*)(ResF + ((long long)row << 8)) + lane);
    ushort4 ub;
    ub.x = f2bf(v0 + rr.x); ub.y = f2bf(v1 + rr.y);
    ub.z = f2bf(v2 + rr.z); ub.w = f2bf(v3 + rr.w);
    *((ushort4*)(OutB + ((long long)row << 9)) + lane) = ub;
  } else if constexpr (MODE == 1) {
    ushort4 ub; ub.x = f2bf(v0); ub.y = f2bf(v1); ub.z = f2bf(v2); ub.w = f2bf(v3);
    *((ushort4*)(OutB + ((long long)row << 9) + 256) + lane) = ub;
  } else {
    ushort4 rb = *((const ushort4*)(ResB + ((long long)row << 9)) + lane);
    float4 o;
    o.x = v0 + bf2f(rb.x); o.y = v1 + bf2f(rb.y);
    o.z = v2 + bf2f(rb.z); o.w = v3 + bf2f(rb.w);
    *((float4*)(OutF + ((long long)row << 8)) + lane) = o;
  }
}

// ---------- fp32 -> bf16 convert (vectorized) ----------
__global__ __launch_bounds__(256)
void cvt_f32_bf16(const float* __restrict__ src, u16* __restrict__ dst, int n4)
{
  int i = blockIdx.x * 256 + threadIdx.x;
  if (i >= n4) return;
  float4 v = ((const float4*)src)[i];
  ushort4 u; u.x = f2bf(v.x); u.y = f2bf(v.y); u.z = f2bf(v.z); u.w = f2bf(v.w);
  ((ushort4*)dst)[i] = u;
}

// ---------- weight transpose fp32 [R][C] -> bf16 [C][R] ----------
__global__ __launch_bounds__(256)
void wtrans(const float* __restrict__ src, u16* __restrict__ dst, int R, int C)
{
  int idx = blockIdx.x * 256 + threadIdx.x;
  if (idx >= R * C) return;
  int r = idx / C, c = idx - r * C;
  dst[c * R + r] = f2bf(src[idx]);
}

// ---------- orchestration ----------
extern "C" void kernel_launch(void* const* d_in, const int* in_sizes, int n_in,
                              void* d_out, int out_size, void* d_ws, size_t ws_size,
                              hipStream_t stream)
{
  (void)in_sizes; (void)n_in; (void)out_size;
  const float* feat0 = (const float*)d_in[0];
  const float* feat1 = (const float*)d_in[1];
  const float* mask  = (const float*)d_in[2];
  const float* wq1 = (const float*)d_in[6];
  const float* wk1 = (const float*)d_in[7];
  const float* wv1 = (const float*)d_in[8];
  const float* wf1 = (const float*)d_in[9];
  const float* g1  = (const float*)d_in[10];
  const float* b1  = (const float*)d_in[11];
  const float* wq2 = (const float*)d_in[12];
  const float* wk2 = (const float*)d_in[13];
  const float* wv2 = (const float*)d_in[14];
  const float* wf2 = (const float*)d_in[15];
  const float* g2  = (const float*)d_in[16];
  const float* b2  = (const float*)d_in[17];
  const float* w1  = (const float*)d_in[18];
  const float* w2  = (const float*)d_in[19];
  const float* fg  = (const float*)d_in[20];
  const float* fb  = (const float*)d_in[21];

  const size_t Mi = 1048576;
  const size_t WB = 4 * Mi;            // weights: 1 MiB (8x 256x256) + 2 MiB (w1t) + 1 MiB (w2t)
  const int Mtot = 131072;

  // pick chunk count: smallest nc in {1,2,4,8} with 7*S + WB <= ws_size
  int nc = 8;
  for (int c = 1; c <= 8; c <<= 1) {
    size_t S = (size_t)(Mtot / c) * 512;  // bytes per 64 MiB/nc unit
    if (7 * S + WB <= ws_size) { nc = c; break; }
  }
  const int Mc = Mtot / nc;            // tokens per chunk
  const size_t S = (size_t)Mc * 512;   // bytes of one Mc x 256 bf16 buffer

  char* ws = (char*)d_ws;
  // per-chunk arena (aliased; single-stream ordering serializes hazards)
  u16*   featb = (u16*)(ws);           // featN bf16; later scores/probs SPb
  u16*   SPb   = featb;
  u16*   qw    = (u16*)(ws + S);       // q windowed; later attn-out Ob; later FFN hidden hc
  u16*   Ob    = qw;
  u16*   hc    = qw;
  u16*   kw    = (u16*)(ws + 2 * S);   // k windowed; later y (fp32, spans 2S..4S)
  u16*   vw    = (u16*)(ws + 3 * S);   // v windowed
  float* y     = (float*)(ws + 2 * S); // fp32 Mc x 256 = 2S bytes
  u16*   vt    = (u16*)(ws + 4 * S);   // v^T per window
  u16*   xcat  = (u16*)(ws + 5 * S);   // [Mc, 512] bf16: [f0 | a2]  (2S bytes)
  u16*   wb    = (u16*)(ws + 7 * S);   // weights, bf16 transposed
  u16* wq1t = wb;            u16* wk1t = wb + 65536;  u16* wv1t = wb + 131072; u16* wf1t = wb + 196608;
  u16* wq2t = wb + 262144;   u16* wk2t = wb + 327680; u16* wv2t = wb + 393216; u16* wf2t = wb + 458752;
  u16* w1t  = wb + 524288;               // [2048][512]
  u16* w2t  = wb + 524288 + 1048576;     // [256][2048]

  const dim3 blk(256);
  const dim3 gBig(Mc / 128, 2, 1);
  const int  Wc = Mc / 256;            // windows per chunk
  const dim3 gWin(2, 2, Wc);
  const dim3 gTr(8, 8, Wc);
  const int  gRows = Mc / 4;

  // weights to bf16 (once)
  wtrans<<<256, blk, 0, stream>>>(wq1, wq1t, 256, 256);
  wtrans<<<256, blk, 0, stream>>>(wk1, wk1t, 256, 256);
  wtrans<<<256, blk, 0, stream>>>(wv1, wv1t, 256, 256);
  wtrans<<<256, blk, 0, stream>>>(wf1, wf1t, 256, 256);
  wtrans<<<256, blk, 0, stream>>>(wq2, wq2t, 256, 256);
  wtrans<<<256, blk, 0, stream>>>(wk2, wk2t, 256, 256);
  wtrans<<<256, blk, 0, stream>>>(wv2, wv2t, 256, 256);
  wtrans<<<256, blk, 0, stream>>>(wf2, wf2t, 256, 256);
  wtrans<<<4096, blk, 0, stream>>>(w1, w1t, 512, 2048);
  wtrans<<<2048, blk, 0, stream>>>(w2, w2t, 2048, 256);

  for (int c = 0; c < nc; ++c) {
    const long long off = (long long)c * Mc * 256;   // elements (tokens x 256)
    const float* f0in = feat0 + off;
    const float* f1in = feat1 + off;
    float* outp = (float*)d_out + off;

    // ---- Block 1 (intra): q,k,v from feat0 ----
    cvt_f32_bf16<<<gRows, blk, 0, stream>>>(f0in, featb, Mc * 64);
    gemm_nt<MODE_QKV><<<gBig, blk, 0, stream>>>(featb, 256, 0, wq1t, 256, 0, qw, nullptr, nullptr, 256, 0);
    gemm_nt<MODE_QKV><<<gBig, blk, 0, stream>>>(featb, 256, 0, wk1t, 256, 0, kw, nullptr, nullptr, 256, 0);
    gemm_nt<MODE_QKV><<<gBig, blk, 0, stream>>>(featb, 256, 0, wv1t, 256, 0, vw, nullptr, nullptr, 256, 0);
    transpose256<<<gTr, blk, 0, stream>>>(vw, vt);
    gemm_nt<MODE_SCORES><<<gWin, blk, 0, stream>>>(qw, 256, 65536, kw, 256, 65536, SPb, nullptr, mask, 256, 0);
    softmax_rows<<<gRows, blk, 0, stream>>>(SPb);
    gemm_nt<MODE_PV><<<gWin, blk, 0, stream>>>(SPb, 256, 65536, vt, 256, 65536, Ob, nullptr, nullptr, 256, 0);
    gemm_nt<MODE_F32><<<gBig, blk, 0, stream>>>(Ob, 256, 0, wf1t, 256, 0, nullptr, y, nullptr, 256, 0);
    ln_kernel<0><<<gRows, blk, 0, stream>>>(y, g1, b1, f0in, nullptr, nullptr, xcat);

    // ---- Block 2 (inter): q from f0 (xcat[:, :256]), k,v from feat1 ----
    cvt_f32_bf16<<<gRows, blk, 0, stream>>>(f1in, featb, Mc * 64);
    gemm_nt<MODE_QKV><<<gBig, blk, 0, stream>>>(xcat, 512, 0, wq2t, 256, 0, qw, nullptr, nullptr, 256, 0);
    gemm_nt<MODE_QKV><<<gBig, blk, 0, stream>>>(featb, 256, 0, wk2t, 256, 0, kw, nullptr, nullptr, 256, 0);
    gemm_nt<MODE_QKV><<<gBig, blk, 0, stream>>>(featb, 256, 0, wv2t, 256, 0, vw, nullptr, nullptr, 256, 0);
    transpose256<<<gTr, blk, 0, stream>>>(vw, vt);
    gemm_nt<MODE_SCORES><<<gWin, blk, 0, stream>>>(qw, 256, 65536, kw, 256, 65536, SPb, nullptr, mask, 256, 0);
    softmax_rows<<<gRows, blk, 0, stream>>>(SPb);
    gemm_nt<MODE_PV><<<gWin, blk, 0, stream>>>(SPb, 256, 65536, vt, 256, 65536, Ob, nullptr, nullptr, 256, 0);
    gemm_nt<MODE_F32><<<gBig, blk, 0, stream>>>(Ob, 256, 0, wf2t, 256, 0, nullptr, y, nullptr, 256, 0);
    ln_kernel<1><<<gRows, blk, 0, stream>>>(y, g2, b2, nullptr, nullptr, nullptr, xcat);

    // ---- FFN: h = gelu(xcat @ w1) chunked over 2048 hidden; y = h @ w2 (fp32 accum) ----
    for (int j = 0; j < 8; ++j) {
      gemm_nt<MODE_FFN1><<<gBig, blk, 0, stream>>>(xcat, 512, 0, w1t + (size_t)j * 131072, 512, 0,
                                                   hc, nullptr, nullptr, 512, 0);
      gemm_nt<MODE_F32><<<gBig, blk, 0, stream>>>(hc, 256, 0, w2t + (size_t)j * 256, 2048, 0,
                                                  nullptr, y, nullptr, 256, j);
    }
    ln_kernel<2><<<gRows, blk, 0, stream>>>(y, fg, fb, nullptr, xcat, outp, nullptr);
  }
}

// Round 3
// 2118.979 us; speedup vs baseline: 1.2400x; 1.2400x over previous
//
#include <hip/hip_runtime.h>

typedef unsigned short u16;
typedef unsigned int   u32;

using f32x4  = __attribute__((ext_vector_type(4))) float;
using bf16x8 = __attribute__((ext_vector_type(8))) __bf16;

// ---------- helpers ----------
__device__ inline u16 f2bf(float f) {
  u32 u = __builtin_bit_cast(u32, f);
  u32 r = (u + 0x7FFFu + ((u >> 16) & 1u)) >> 16;   // RNE
  return (u16)r;
}
__device__ inline float bf2f(u16 v) {
  u32 u = ((u32)v) << 16;
  return __builtin_bit_cast(float, u);
}

// async global->LDS, 16B per lane; dst is wave-uniform base + lane*16
__device__ inline void gl_lds16(const u16* g, u16* l) {
  __builtin_amdgcn_global_load_lds((const __attribute__((address_space(1))) void*)g,
                                   (__attribute__((address_space(3))) void*)l,
                                   16, 0, 0);
}

// Geometry: B=8, H=W=128, NW=8, win=16x16 (N=256), D=256, shift=8. Chunk-local.
__device__ inline int perm_fwd(int m) {
  int b = m >> 14, rem = m & 16383;
  int h = rem >> 7, w = rem & 127;
  int hr = (h - 8) & 127, wr = (w - 8) & 127;
  int win = (b << 6) | ((hr >> 4) << 3) | (wr >> 4);
  return (win << 8) | ((hr & 15) << 4) | (wr & 15);
}
__device__ inline int perm_inv(int r) {
  int win = r >> 8, t = r & 255;
  int b = win >> 6, wy = (win >> 3) & 7, wx = win & 7;
  int h = (((wy << 4) | (t >> 4)) + 8) & 127;
  int w = (((wx << 4) | (t & 15)) + 8) & 127;
  return (b << 14) | (h << 7) | w;
}

// ---------- 128x128x(BK=32) NT GEMM, bf16 in / fp32 acc, global_load_lds staging ----------
// LDS tile: 128 rows x 32 elems (64B rows), XOR-swizzled: slot(row, c16) holds
// global 16B-chunk c16 ^ ((row>>1)&3). No padding (required by global_load_lds).

enum { MODE_QKV = 0, MODE_SCORES = 1, MODE_PV = 2, MODE_F32 = 3, MODE_FFN1 = 4 };

template<int MODE>
__global__ __launch_bounds__(256)
void gemm_nt(const u16* __restrict__ A, int lda, long long sAz,
             const u16* __restrict__ Bt, int ldb, long long sBz,
             u16* __restrict__ OutB, float* __restrict__ OutF,
             const float* __restrict__ mask, int K, int ldo)
{
  __shared__ __align__(16) u16 sA[128 * 32];
  __shared__ __align__(16) u16 sB[128 * 32];

  const int tid  = threadIdx.x;
  const int lane = tid & 63;
  const int wave = tid >> 6;
  const int l15  = lane & 15;
  const int quad = lane >> 4;
  const int wm   = (wave >> 1) << 6;
  const int wn   = (wave & 1) << 6;
  const int z    = blockIdx.z;
  const int m0   = (int)(blockIdx.y) << 7;
  const int n0   = (int)(blockIdx.x) << 7;

  const u16* Ab = A  + (long long)z * sAz;
  const u16* Bb = Bt + (long long)z * sBz;

  // staging: wave w stages A rows [32w,32w+32) and B rows [32w,32w+32)
  // lane l: row-in-16 = l>>2, chunk slot = l&3, data chunk = (l&3)^((l>>3)&3)
  const int cd = ((lane & 3) ^ ((lane >> 3) & 3)) << 3;   // elems
  const int rs = (wave << 5) + (lane >> 2);
  const u16* ga0 = Ab + (long long)(m0 + rs) * lda + cd;
  const u16* ga1 = ga0 + 16ll * lda;
  const u16* gb0 = Bb + (long long)(n0 + rs) * ldb + cd;
  const u16* gb1 = gb0 + 16ll * ldb;
  u16* la0 = &sA[wave << 10];
  u16* la1 = la0 + 512;
  u16* lb0 = &sB[wave << 10];
  u16* lb1 = lb0 + 512;

  // fragment-read swizzle offset (lane-constant)
  const int sw = ((((l15 >> 1) & 3) ^ quad) << 3);

  const f32x4 zero = {0.f, 0.f, 0.f, 0.f};
  f32x4 acc[4][4];
#pragma unroll
  for (int i = 0; i < 4; ++i)
#pragma unroll
    for (int j = 0; j < 4; ++j) acc[i][j] = zero;

  for (int k0 = 0; k0 < K; k0 += 32) {
    __syncthreads();
    gl_lds16(ga0 + k0, la0);
    gl_lds16(ga1 + k0, la1);
    gl_lds16(gb0 + k0, lb0);
    gl_lds16(gb1 + k0, lb1);
    __syncthreads();
    bf16x8 af[4], bfr[4];
#pragma unroll
    for (int i = 0; i < 4; ++i) {
      af[i]  = *(const bf16x8*)(sA + ((wm + (i << 4) + l15) << 5) + sw);
      bfr[i] = *(const bf16x8*)(sB + ((wn + (i << 4) + l15) << 5) + sw);
    }
#pragma unroll
    for (int i = 0; i < 4; ++i)
#pragma unroll
      for (int j = 0; j < 4; ++j)
        acc[i][j] = __builtin_amdgcn_mfma_f32_16x16x32_bf16(af[i], bfr[j], acc[i][j], 0, 0, 0);
  }

  // epilogue: D[row=quad*4+r][col=l15]
#pragma unroll
  for (int i = 0; i < 4; ++i) {
#pragma unroll
    for (int r = 0; r < 4; ++r) {
      int mg = m0 + wm + (i << 4) + (quad << 2) + r;
      if constexpr (MODE == MODE_QKV) {
        u16* orow = OutB + ((long long)perm_fwd(mg) << 8);
#pragma unroll
        for (int j = 0; j < 4; ++j) {
          int ng = n0 + wn + (j << 4) + l15;
          orow[ng] = f2bf(acc[i][j][r]);
        }
      } else if constexpr (MODE == MODE_SCORES) {
        const float* mrow = mask + (((long long)(z & 63)) << 16) + ((long long)mg << 8);
        u16* orow = OutB + (((long long)z) << 16) + ((long long)mg << 8);
#pragma unroll
        for (int j = 0; j < 4; ++j) {
          int ng = n0 + wn + (j << 4) + l15;
          orow[ng] = f2bf(acc[i][j][r] * 0.0625f + mrow[ng]);
        }
      } else if constexpr (MODE == MODE_PV) {
        u16* orow = OutB + ((long long)perm_inv((z << 8) + mg) << 8);
#pragma unroll
        for (int j = 0; j < 4; ++j) {
          int ng = n0 + wn + (j << 4) + l15;
          orow[ng] = f2bf(acc[i][j][r]);
        }
      } else if constexpr (MODE == MODE_F32) {
        float* orow = OutF + ((long long)mg << 8);
#pragma unroll
        for (int j = 0; j < 4; ++j) {
          int ng = n0 + wn + (j << 4) + l15;
          orow[ng] = acc[i][j][r];
        }
      } else { // MODE_FFN1: exact gelu -> bf16, ld = ldo
        u16* orow = OutB + (long long)mg * ldo;
#pragma unroll
        for (int j = 0; j < 4; ++j) {
          int ng = n0 + wn + (j << 4) + l15;
          float v = acc[i][j][r];
          orow[ng] = f2bf(0.5f * v * (1.0f + erff(v * 0.70710678118654752f)));
        }
      }
    }
  }
}

// ---------- per-window 256x256 transpose (bf16) ----------
__global__ __launch_bounds__(256)
void transpose256(const u16* __restrict__ src, u16* __restrict__ dst)
{
  __shared__ u16 t[32][33];
  const int z  = blockIdx.z;
  const int tx = blockIdx.x << 5;
  const int ty = blockIdx.y << 5;
  const int c  = threadIdx.x & 31;
  const int r0 = threadIdx.x >> 5;
  const long long base = ((long long)z) << 16;
#pragma unroll
  for (int p = 0; p < 4; ++p) {
    int r = r0 + (p << 3);
    t[r][c] = src[base + (long long)(ty + r) * 256 + tx + c];
  }
  __syncthreads();
#pragma unroll
  for (int p = 0; p < 4; ++p) {
    int r = r0 + (p << 3);
    dst[base + (long long)(tx + r) * 256 + ty + c] = t[c][r];
  }
}

// ---------- in-place row softmax over 256 bf16 (1 wave/row) ----------
__global__ __launch_bounds__(256)
void softmax_rows(u16* __restrict__ SP)
{
  const int row  = (blockIdx.x << 2) + (threadIdx.x >> 6);
  const int lane = threadIdx.x & 63;
  u16* rp = SP + ((long long)row << 8);
  ushort4 u = *((const ushort4*)rp + lane);
  float x0 = bf2f(u.x), x1 = bf2f(u.y), x2 = bf2f(u.z), x3 = bf2f(u.w);
  float mx = fmaxf(fmaxf(x0, x1), fmaxf(x2, x3));
#pragma unroll
  for (int o = 32; o > 0; o >>= 1) mx = fmaxf(mx, __shfl_xor(mx, o));
  float e0 = __expf(x0 - mx), e1 = __expf(x1 - mx), e2 = __expf(x2 - mx), e3 = __expf(x3 - mx);
  float s = e0 + e1 + e2 + e3;
#pragma unroll
  for (int o = 32; o > 0; o >>= 1) s += __shfl_xor(s, o);
  float inv = 1.0f / s;
  ushort4 o4;
  o4.x = f2bf(e0 * inv); o4.y = f2bf(e1 * inv); o4.z = f2bf(e2 * inv); o4.w = f2bf(e3 * inv);
  *((ushort4*)rp + lane) = o4;
}

// ---------- LayerNorm variants (1 wave/row, 256 cols) ----------
template<int MODE>
__global__ __launch_bounds__(256)
void ln_kernel(const float* __restrict__ Y, const float* __restrict__ G,
               const float* __restrict__ Bb, const float* __restrict__ ResF,
               const u16* __restrict__ ResB,
               float* __restrict__ OutF, u16* __restrict__ OutB)
{
  const int row  = (blockIdx.x << 2) + (threadIdx.x >> 6);
  const int lane = threadIdx.x & 63;
  float4 x = *((const float4*)(Y + ((long long)row << 8)) + lane);
  float s  = x.x + x.y + x.z + x.w;
  float s2 = x.x * x.x + x.y * x.y + x.z * x.z + x.w * x.w;
#pragma unroll
  for (int o = 32; o > 0; o >>= 1) { s += __shfl_xor(s, o); s2 += __shfl_xor(s2, o); }
  float mean = s * (1.0f / 256.0f);
  float var  = s2 * (1.0f / 256.0f) - mean * mean;
  float rstd = rsqrtf(var + 1e-5f);
  float4 g = *((const float4*)G + lane);
  float4 b = *((const float4*)Bb + lane);
  float v0 = (x.x - mean) * rstd * g.x + b.x;
  float v1 = (x.y - mean) * rstd * g.y + b.y;
  float v2 = (x.z - mean) * rstd * g.z + b.z;
  float v3 = (x.w - mean) * rstd * g.w + b.w;
  if constexpr (MODE == 0) {
    float4 rr = *((const float4*)(ResF + ((long long)row << 8)) + lane);
    ushort4 ub;
    ub.x = f2bf(v0 + rr.x); ub.y = f2bf(v1 + rr.y);
    ub.z = f2bf(v2 + rr.z); ub.w = f2bf(v3 + rr.w);
    *((ushort4*)(OutB + ((long long)row << 9)) + lane) = ub;
  } else if constexpr (MODE == 1) {
    ushort4 ub; ub.x = f2bf(v0); ub.y = f2bf(v1); ub.z = f2bf(v2); ub.w = f2bf(v3);
    *((ushort4*)(OutB + ((long long)row << 9) + 256) + lane) = ub;
  } else {
    ushort4 rb = *((const ushort4*)(ResB + ((long long)row << 9)) + lane);
    float4 o;
    o.x = v0 + bf2f(rb.x); o.y = v1 + bf2f(rb.y);
    o.z = v2 + bf2f(rb.z); o.w = v3 + bf2f(rb.w);
    *((float4*)(OutF + ((long long)row << 8)) + lane) = o;
  }
}

// ---------- fp32 -> bf16 convert ----------
__global__ __launch_bounds__(256)
void cvt_f32_bf16(const float* __restrict__ src, u16* __restrict__ dst, int n4)
{
  int i = blockIdx.x * 256 + threadIdx.x;
  if (i >= n4) return;
  float4 v = ((const float4*)src)[i];
  ushort4 u; u.x = f2bf(v.x); u.y = f2bf(v.y); u.z = f2bf(v.z); u.w = f2bf(v.w);
  ((ushort4*)dst)[i] = u;
}

// ---------- weight transpose fp32 [R][C] -> bf16 [C][R] ----------
__global__ __launch_bounds__(256)
void wtrans(const float* __restrict__ src, u16* __restrict__ dst, int R, int C)
{
  int idx = blockIdx.x * 256 + threadIdx.x;
  if (idx >= R * C) return;
  int r = idx / C, c = idx - r * C;
  dst[c * R + r] = f2bf(src[idx]);
}

// ---------- orchestration ----------
extern "C" void kernel_launch(void* const* d_in, const int* in_sizes, int n_in,
                              void* d_out, int out_size, void* d_ws, size_t ws_size,
                              hipStream_t stream)
{
  (void)in_sizes; (void)n_in; (void)out_size;
  const float* feat0 = (const float*)d_in[0];
  const float* feat1 = (const float*)d_in[1];
  const float* mask  = (const float*)d_in[2];
  const float* wq1 = (const float*)d_in[6];
  const float* wk1 = (const float*)d_in[7];
  const float* wv1 = (const float*)d_in[8];
  const float* wf1 = (const float*)d_in[9];
  const float* g1  = (const float*)d_in[10];
  const float* b1  = (const float*)d_in[11];
  const float* wq2 = (const float*)d_in[12];
  const float* wk2 = (const float*)d_in[13];
  const float* wv2 = (const float*)d_in[14];
  const float* wf2 = (const float*)d_in[15];
  const float* g2  = (const float*)d_in[16];
  const float* b2  = (const float*)d_in[17];
  const float* w1  = (const float*)d_in[18];
  const float* w2  = (const float*)d_in[19];
  const float* fg  = (const float*)d_in[20];
  const float* fb  = (const float*)d_in[21];

  const size_t Mi = 1048576;
  const size_t WB = 4 * Mi;
  const int Mtot = 131072;

  int nc = 8;
  for (int c = 1; c <= 8; c <<= 1) {
    size_t S = (size_t)(Mtot / c) * 512;
    if (7 * S + WB <= ws_size) { nc = c; break; }
  }
  const int Mc = Mtot / nc;
  const size_t S = (size_t)Mc * 512;

  char* ws = (char*)d_ws;
  u16*   featb = (u16*)(ws);           // featN bf16; later scores SPb; later hbuf (w/ qw)
  u16*   SPb   = featb;
  u16*   qw    = (u16*)(ws + S);       // q windowed; later attn-out Ob
  u16*   Ob    = qw;
  u16*   hbuf  = featb;                // FFN hidden [MF, 2048] bf16 = 2S bytes (featb+qw)
  u16*   kw    = (u16*)(ws + 2 * S);   // k windowed; later y fp32
  u16*   vw    = (u16*)(ws + 3 * S);   // v windowed
  float* y     = (float*)(ws + 2 * S);
  u16*   vt    = (u16*)(ws + 4 * S);   // v^T per window
  u16*   xcat  = (u16*)(ws + 5 * S);   // [Mc, 512] bf16: [f0 | a2]
  u16*   wb    = (u16*)(ws + 7 * S);
  u16* wq1t = wb;            u16* wk1t = wb + 65536;  u16* wv1t = wb + 131072; u16* wf1t = wb + 196608;
  u16* wq2t = wb + 262144;   u16* wk2t = wb + 327680; u16* wv2t = wb + 393216; u16* wf2t = wb + 458752;
  u16* w1t  = wb + 524288;               // [2048][512]
  u16* w2t  = wb + 524288 + 1048576;     // [256][2048]

  const dim3 blk(256);
  const dim3 gBig(2, Mc / 128, 1);     // x = N tiles, y = M tiles
  const int  Wc = Mc / 256;
  const dim3 gWin(2, 2, Wc);
  const dim3 gTr(8, 8, Wc);
  const int  gRows = Mc / 4;
  const int  MF = Mc / 4;              // FFN M-chunk rows
  const dim3 gF1(16, MF / 128, 1);
  const dim3 gF2(2, MF / 128, 1);
  const int  gRowsF = MF / 4;

  wtrans<<<256, blk, 0, stream>>>(wq1, wq1t, 256, 256);
  wtrans<<<256, blk, 0, stream>>>(wk1, wk1t, 256, 256);
  wtrans<<<256, blk, 0, stream>>>(wv1, wv1t, 256, 256);
  wtrans<<<256, blk, 0, stream>>>(wf1, wf1t, 256, 256);
  wtrans<<<256, blk, 0, stream>>>(wq2, wq2t, 256, 256);
  wtrans<<<256, blk, 0, stream>>>(wk2, wk2t, 256, 256);
  wtrans<<<256, blk, 0, stream>>>(wv2, wv2t, 256, 256);
  wtrans<<<256, blk, 0, stream>>>(wf2, wf2t, 256, 256);
  wtrans<<<4096, blk, 0, stream>>>(w1, w1t, 512, 2048);
  wtrans<<<2048, blk, 0, stream>>>(w2, w2t, 2048, 256);

  for (int c = 0; c < nc; ++c) {
    const long long off = (long long)c * Mc * 256;
    const float* f0in = feat0 + off;
    const float* f1in = feat1 + off;
    float* outp = (float*)d_out + off;

    // ---- Block 1 (intra) ----
    cvt_f32_bf16<<<gRows, blk, 0, stream>>>(f0in, featb, Mc * 64);
    gemm_nt<MODE_QKV><<<gBig, blk, 0, stream>>>(featb, 256, 0, wq1t, 256, 0, qw, nullptr, nullptr, 256, 0);
    gemm_nt<MODE_QKV><<<gBig, blk, 0, stream>>>(featb, 256, 0, wk1t, 256, 0, kw, nullptr, nullptr, 256, 0);
    gemm_nt<MODE_QKV><<<gBig, blk, 0, stream>>>(featb, 256, 0, wv1t, 256, 0, vw, nullptr, nullptr, 256, 0);
    transpose256<<<gTr, blk, 0, stream>>>(vw, vt);
    gemm_nt<MODE_SCORES><<<gWin, blk, 0, stream>>>(qw, 256, 65536, kw, 256, 65536, SPb, nullptr, mask, 256, 0);
    softmax_rows<<<gRows, blk, 0, stream>>>(SPb);
    gemm_nt<MODE_PV><<<gWin, blk, 0, stream>>>(SPb, 256, 65536, vt, 256, 65536, Ob, nullptr, nullptr, 256, 0);
    gemm_nt<MODE_F32><<<gBig, blk, 0, stream>>>(Ob, 256, 0, wf1t, 256, 0, nullptr, y, nullptr, 256, 0);
    ln_kernel<0><<<gRows, blk, 0, stream>>>(y, g1, b1, f0in, nullptr, nullptr, xcat);

    // ---- Block 2 (inter) ----
    cvt_f32_bf16<<<gRows, blk, 0, stream>>>(f1in, featb, Mc * 64);
    gemm_nt<MODE_QKV><<<gBig, blk, 0, stream>>>(xcat, 512, 0, wq2t, 256, 0, qw, nullptr, nullptr, 256, 0);
    gemm_nt<MODE_QKV><<<gBig, blk, 0, stream>>>(featb, 256, 0, wk2t, 256, 0, kw, nullptr, nullptr, 256, 0);
    gemm_nt<MODE_QKV><<<gBig, blk, 0, stream>>>(featb, 256, 0, wv2t, 256, 0, vw, nullptr, nullptr, 256, 0);
    transpose256<<<gTr, blk, 0, stream>>>(vw, vt);
    gemm_nt<MODE_SCORES><<<gWin, blk, 0, stream>>>(qw, 256, 65536, kw, 256, 65536, SPb, nullptr, mask, 256, 0);
    softmax_rows<<<gRows, blk, 0, stream>>>(SPb);
    gemm_nt<MODE_PV><<<gWin, blk, 0, stream>>>(SPb, 256, 65536, vt, 256, 65536, Ob, nullptr, nullptr, 256, 0);
    gemm_nt<MODE_F32><<<gBig, blk, 0, stream>>>(Ob, 256, 0, wf2t, 256, 0, nullptr, y, nullptr, 256, 0);
    ln_kernel<1><<<gRows, blk, 0, stream>>>(y, g2, b2, nullptr, nullptr, nullptr, xcat);

    // ---- FFN: M-chunked, hbuf aliases featb+qw (both dead here) ----
    for (int mc = 0; mc < 4; ++mc) {
      const u16* xc = xcat + (long long)mc * MF * 512;
      gemm_nt<MODE_FFN1><<<gF1, blk, 0, stream>>>(xc, 512, 0, w1t, 512, 0,
                                                  hbuf, nullptr, nullptr, 512, 2048);
      gemm_nt<MODE_F32><<<gF2, blk, 0, stream>>>(hbuf, 2048, 0, w2t, 2048, 0,
                                                 nullptr, y, nullptr, 2048, 0);
      ln_kernel<2><<<gRowsF, blk, 0, stream>>>(y, fg, fb, nullptr,
                                               xcat + (long long)mc * MF * 512,
                                               outp + (long long)mc * MF * 256, nullptr);
    }
  }
}